// Round 3
// baseline (389.558 us; speedup 1.0000x reference)
//
#include <hip/hip_runtime.h>
#include <hip/hip_bf16.h>

// Problem constants
constexpr int kH  = 8;     // heads
constexpr int kD  = 16;    // dim per head
constexpr int kHD = 128;   // H*D
constexpr int kN  = 32;    // neighbors
constexpr int kE  = 32;    // edge feature dim
constexpr int kD0 = 128;   // feats0 channels
constexpr int kD1 = 64;    // feats1 channels

constexpr float SCALE0   = 0.25f;                 // 1/sqrt(16)
constexpr float SCALE1   = 0.14433756729740643f;  // 1/sqrt(48)
constexpr float SHARED_S = 0.70710678118654752f;  // sqrt(0.5)
constexpr float NEGV     = -1e9f;

// ws layout (floats): sc[n][8][34] | sv0[n][128] | sv1[n][384]

// ---------------------------------------------------------------------------
// K1: self key/value rows + null/self similarity score slots.
// Block per position, 256 threads (one W_self_kv row each).
// ---------------------------------------------------------------------------
__global__ __launch_bounds__(256) void k1_selfkv(
    const float* __restrict__ q0, const float* __restrict__ q1,
    const float* __restrict__ feats0, const float* __restrict__ feats1,
    const float* __restrict__ Wskv0, const float* __restrict__ Wskv1,
    const float* __restrict__ self_bias, const float* __restrict__ null_bias,
    const float* __restrict__ nk0, const float* __restrict__ nk1,
    const float* __restrict__ hw1,
    float* __restrict__ ws_sc, float* __restrict__ ws_sv0, float* __restrict__ ws_sv1)
{
  const int i = blockIdx.x;
  const int t = threadIdx.x;
  __shared__ float f0s[kD0];
  __shared__ float f1s[kD1 * 3];
  __shared__ float q0s[kHD];
  __shared__ float q1s[kHD * 3];
  __shared__ float sk0[kHD];
  __shared__ float sk1[kHD * 3];
  __shared__ float w1s[kH];

  if (t < kD0)     f0s[t] = feats0[(size_t)i * kD0 + t];
  if (t < kD1 * 3) f1s[t] = feats1[(size_t)i * kD1 * 3 + t];
  if (t < kHD)     q0s[t] = q0[(size_t)i * kHD + t];
  for (int u = t; u < kHD * 3; u += 256) q1s[u] = q1[(size_t)i * kHD * 3 + u];
  if (t < kH) w1s[t] = log1pf(expf(hw1[t]));
  __syncthreads();

  // row t of W_self_kv (first 128 rows -> self-k, last 128 -> self-v)
  float acc = 0.f;
  {
    const float4* wr = (const float4*)(Wskv0 + t * kD0);
    #pragma unroll
    for (int g = 0; g < 32; ++g) {
      float4 w = wr[g];
      int c = g * 4;
      acc += w.x * f0s[c] + w.y * f0s[c + 1] + w.z * f0s[c + 2] + w.w * f0s[c + 3];
    }
  }
  float a0 = 0.f, a1 = 0.f, a2 = 0.f;
  {
    const float4* wr = (const float4*)(Wskv1 + t * kD1);
    #pragma unroll
    for (int g = 0; g < 16; ++g) {
      float4 w = wr[g];
      int c = g * 4;
      a0 += w.x * f1s[(c + 0) * 3 + 0] + w.y * f1s[(c + 1) * 3 + 0]
          + w.z * f1s[(c + 2) * 3 + 0] + w.w * f1s[(c + 3) * 3 + 0];
      a1 += w.x * f1s[(c + 0) * 3 + 1] + w.y * f1s[(c + 1) * 3 + 1]
          + w.z * f1s[(c + 2) * 3 + 1] + w.w * f1s[(c + 3) * 3 + 1];
      a2 += w.x * f1s[(c + 0) * 3 + 2] + w.y * f1s[(c + 1) * 3 + 2]
          + w.z * f1s[(c + 2) * 3 + 2] + w.w * f1s[(c + 3) * 3 + 2];
    }
  }
  if (t < kHD) {
    sk0[t] = acc;
    sk1[t * 3 + 0] = a0; sk1[t * 3 + 1] = a1; sk1[t * 3 + 2] = a2;
  } else {
    const int o = t - kHD;
    ws_sv0[(size_t)i * kHD + o] = acc;
    float* sp = ws_sv1 + (size_t)i * kHD * 3 + o * 3;
    sp[0] = a0; sp[1] = a1; sp[2] = a2;
  }
  __syncthreads();

  if (t < 2 * kH) {
    const int h = t & 7;
    const bool is_self = t >= kH;
    float s0 = 0.f, s1 = 0.f, bias;
    if (is_self) {
      #pragma unroll
      for (int d = 0; d < kD; ++d) s0 += q0s[h * kD + d] * sk0[h * kD + d];
      #pragma unroll
      for (int x = 0; x < 48; ++x) s1 += q1s[h * 48 + x] * sk1[h * 48 + x];
      bias = self_bias[h];
    } else {
      #pragma unroll
      for (int d = 0; d < kD; ++d) s0 += q0s[h * kD + d] * nk0[h * kD + d];
      #pragma unroll
      for (int x = 0; x < 48; ++x) s1 += q1s[h * 48 + x] * nk1[h * 48 + x];
      bias = null_bias[h];
    }
    float total = (s0 * SCALE0 + bias + s1 * SCALE1 * w1s[h]) * SHARED_S;
    ws_sc[(size_t)i * 272 + h * 34 + (is_self ? 1 : 0)] = total;
  }
}

// ---------------------------------------------------------------------------
// K2: neighbor similarities + fused softmax (needs K1's score slots 0,1).
// Block per position; thread (j,h) = (t>>3, t&7).
// ---------------------------------------------------------------------------
__global__ __launch_bounds__(256) void k2_sims(
    const float* __restrict__ q0, const float* __restrict__ q1,
    const float* __restrict__ k0, const float* __restrict__ k1,
    const float* __restrict__ edges, const float* __restrict__ Wbias,
    const float* __restrict__ hw1, const int* __restrict__ nmask,
    float* __restrict__ ws_sc)
{
  const int i = blockIdx.x;
  const int t = threadIdx.x;
  __shared__ float q0s[kH * 17];     // [h*17+d] padded
  __shared__ float q1s[kH * 49];     // [h*49+x] padded
  __shared__ float edg[kN * 33];     // [j*33+e] padded
  __shared__ float wbT[kE * kH];     // [e*8+h]
  __shared__ float w1s[kH];
  __shared__ float scL[kH][34];

  if (t < kHD) {
    int h = t >> 4, d = t & 15;
    q0s[h * 17 + d] = q0[(size_t)i * kHD + t];
  }
  for (int u = t; u < kHD * 3; u += 256) {
    int c = u / 3, m = u - c * 3;
    int h = c >> 4, d = c & 15;
    q1s[h * 49 + d * 3 + m] = q1[(size_t)i * kHD * 3 + u];
  }
  for (int u = t; u < kN * kE; u += 256) {
    int j = u >> 5, e = u & 31;
    edg[j * 33 + e] = edges[(size_t)i * kN * kE + u];
  }
  if (t < kH * kE) {
    int h = t >> 5, e = t & 31;
    wbT[e * 8 + h] = Wbias[t];
  }
  if (t < kH) w1s[t] = log1pf(expf(hw1[t]));
  // stage null/self scores from K1
  if (t < 16) scL[t & 7][t >> 3] = ws_sc[(size_t)i * 272 + (t & 7) * 34 + (t >> 3)];
  __syncthreads();

  {
    const int j = t >> 3, h = t & 7;
    float bias = 0.f;
    #pragma unroll
    for (int e = 0; e < kE; ++e) bias += edg[j * 33 + e] * wbT[e * 8 + h];
    float s0 = 0.f;
    {
      const float4* kr = (const float4*)(k0 + (size_t)(i * kN + j) * kHD + h * kD);
      #pragma unroll
      for (int g = 0; g < 4; ++g) {
        float4 w = kr[g];
        int x = h * 17 + g * 4;
        s0 += w.x * q0s[x] + w.y * q0s[x + 1] + w.z * q0s[x + 2] + w.w * q0s[x + 3];
      }
    }
    float s1 = 0.f;
    {
      const float4* kr = (const float4*)(k1 + (size_t)(i * kN + j) * kHD * 3 + h * 48);
      #pragma unroll
      for (int g = 0; g < 12; ++g) {
        float4 w = kr[g];
        int x = h * 49 + g * 4;
        s1 += w.x * q1s[x] + w.y * q1s[x + 1] + w.z * q1s[x + 2] + w.w * q1s[x + 3];
      }
    }
    float total = (s0 * SCALE0 + bias + s1 * SCALE1 * w1s[h]) * SHARED_S;
    bool valid = nmask[(size_t)i * kN + j] != 0;
    scL[h][2 + j] = valid ? total : NEGV;
  }
  __syncthreads();

  if (t < kH) {
    float mx = -1e30f;
    #pragma unroll
    for (int j = 0; j < 34; ++j) mx = fmaxf(mx, scL[t][j]);
    float sum = 0.f;
    #pragma unroll
    for (int j = 0; j < 34; ++j) sum += __expf(scL[t][j] - mx);
    float inv = 1.f / sum;
    float* dst = ws_sc + (size_t)i * 272 + t * 34;
    #pragma unroll
    for (int j = 0; j < 34; ++j) dst[j] = __expf(scL[t][j] - mx) * inv;
  }
}

// ---------------------------------------------------------------------------
// K3: attn-weighted V accumulation (no barrier) + output projections (1 barrier).
// Block per position.
// ---------------------------------------------------------------------------
__global__ __launch_bounds__(256) void k3_out(
    const float* __restrict__ v0, const float* __restrict__ v1,
    const float* __restrict__ nv0, const float* __restrict__ nv1,
    const float* __restrict__ ws_sc,
    const float* __restrict__ ws_sv0, const float* __restrict__ ws_sv1,
    const float* __restrict__ Wout0, const float* __restrict__ Wout1,
    float* __restrict__ out, int n_total)
{
  const int i = blockIdx.x;
  const int t = threadIdx.x;
  __shared__ float o0[kHD];
  __shared__ float o1[kHD * 3];

  if (t < 64) {
    const int c0 = 2 * t;
    const int h = t >> 3;
    const float* at = ws_sc + (size_t)i * 272 + h * 34;
    float ax = at[0] * nv0[c0]     + at[1] * ws_sv0[(size_t)i * kHD + c0];
    float ay = at[0] * nv0[c0 + 1] + at[1] * ws_sv0[(size_t)i * kHD + c0 + 1];
    const float2* vp = (const float2*)(v0 + (size_t)i * kN * kHD) + t;
    #pragma unroll
    for (int j = 0; j < kN; ++j) {
      float2 p = vp[j * 64];
      float a = at[2 + j];
      ax += a * p.x; ay += a * p.y;
    }
    o0[c0] = ax; o0[c0 + 1] = ay;
  } else {
    const int u = t - 64;            // 0..191
    const int f0i = 2 * u;
    const int h = u / 24;
    const float* at = ws_sc + (size_t)i * 272 + h * 34;
    float ax = at[0] * nv1[f0i]     + at[1] * ws_sv1[(size_t)i * kHD * 3 + f0i];
    float ay = at[0] * nv1[f0i + 1] + at[1] * ws_sv1[(size_t)i * kHD * 3 + f0i + 1];
    const float2* vp = (const float2*)(v1 + (size_t)i * kN * kHD * 3) + u;
    #pragma unroll
    for (int j = 0; j < kN; ++j) {
      float2 p = vp[j * 192];
      float a = at[2 + j];
      ax += a * p.x; ay += a * p.y;
    }
    o1[f0i] = ax; o1[f0i + 1] = ay;
  }
  __syncthreads();

  for (int u = t; u < 320; u += 256) {
    if (u < 128) {
      float acc = 0.f;
      const float4* wr = (const float4*)(Wout0 + u * kHD);
      #pragma unroll
      for (int g = 0; g < 32; ++g) {
        float4 w = wr[g];
        int c = g * 4;
        acc += w.x * o0[c] + w.y * o0[c + 1] + w.z * o0[c + 2] + w.w * o0[c + 3];
      }
      out[(size_t)i * kHD + u] = acc;
    } else {
      const int v2 = u - 128;        // (o = v2/3, m = v2%3)
      const int o = v2 / 3, m = v2 - o * 3;
      float acc = 0.f;
      const float4* wr = (const float4*)(Wout1 + o * kHD);
      #pragma unroll
      for (int g = 0; g < 32; ++g) {
        float4 w = wr[g];
        int c = g * 4;
        acc += w.x * o1[(c + 0) * 3 + m] + w.y * o1[(c + 1) * 3 + m]
             + w.z * o1[(c + 2) * 3 + m] + w.w * o1[(c + 3) * 3 + m];
      }
      out[(size_t)n_total * kHD + (size_t)i * 192 + v2] = acc;
    }
  }
}

extern "C" void kernel_launch(void* const* d_in, const int* in_sizes, int n_in,
                              void* d_out, int out_size, void* d_ws, size_t ws_size,
                              hipStream_t stream) {
  const int n = in_sizes[0] / kHD;  // 2048
  const float* q0     = (const float*)d_in[0];
  const float* k0     = (const float*)d_in[1];
  const float* v0     = (const float*)d_in[2];
  const float* q1     = (const float*)d_in[3];
  const float* k1     = (const float*)d_in[4];
  const float* v1     = (const float*)d_in[5];
  const float* feats0 = (const float*)d_in[6];
  const float* feats1 = (const float*)d_in[7];
  const float* edges  = (const float*)d_in[8];
  const float* Wskv0  = (const float*)d_in[9];
  const float* Wskv1  = (const float*)d_in[10];
  const float* Wbias  = (const float*)d_in[11];
  const float* sbias  = (const float*)d_in[12];
  const float* nbias  = (const float*)d_in[13];
  const float* nk0    = (const float*)d_in[14];
  const float* nv0    = (const float*)d_in[15];
  const float* nk1    = (const float*)d_in[16];
  const float* nv1    = (const float*)d_in[17];
  const float* hw1    = (const float*)d_in[18];
  const float* Wout0  = (const float*)d_in[19];
  const float* Wout1  = (const float*)d_in[20];
  const int*   nmask  = (const int*)d_in[21];

  float* ws     = (float*)d_ws;
  float* ws_sc  = ws;                                  // n*272
  float* ws_sv0 = ws + (size_t)n * 272;                // n*128
  float* ws_sv1 = ws + (size_t)n * 272 + (size_t)n * 128;  // n*384

  k1_selfkv<<<n, 256, 0, stream>>>(q0, q1, feats0, feats1, Wskv0, Wskv1,
                                   sbias, nbias, nk0, nk1, hw1,
                                   ws_sc, ws_sv0, ws_sv1);
  k2_sims<<<n, 256, 0, stream>>>(q0, q1, k0, k1, edges, Wbias, hw1, nmask, ws_sc);
  k3_out<<<n, 256, 0, stream>>>(v0, v1, nv0, nv1, ws_sc, ws_sv0, ws_sv1,
                                Wout0, Wout1, (float*)d_out, n);
}

// Round 4
// 381.992 us; speedup vs baseline: 1.0198x; 1.0198x over previous
//
#include <hip/hip_runtime.h>

// Problem constants
constexpr int kH  = 8;     // heads
constexpr int kD  = 16;    // dim per head
constexpr int kHD = 128;   // H*D
constexpr int kN  = 32;    // neighbors
constexpr int kE  = 32;    // edge feature dim
constexpr int kD0 = 128;   // feats0 channels
constexpr int kD1 = 64;    // feats1 channels
constexpr int kP  = 4;     // positions per block

constexpr float SCALE0   = 0.25f;                 // 1/sqrt(16)
constexpr float SCALE1   = 0.14433756729740643f;  // 1/sqrt(48)
constexpr float SHARED_S = 0.70710678118654752f;  // sqrt(0.5)
constexpr float NEGV     = -1e9f;

// ws layout (floats): sc[n][272] | sv0[n][128] | sv1[n][384]

// ---------------------------------------------------------------------------
// K1: self key/value rows + null/self similarity score slots. P positions/block.
// Thread t owns W_self_kv row t; W loaded once, reused for all P positions.
// ---------------------------------------------------------------------------
__global__ __launch_bounds__(256) void k1_selfkv(
    const float* __restrict__ q0, const float* __restrict__ q1,
    const float* __restrict__ feats0, const float* __restrict__ feats1,
    const float* __restrict__ Wskv0, const float* __restrict__ Wskv1,
    const float* __restrict__ self_bias, const float* __restrict__ null_bias,
    const float* __restrict__ nk0, const float* __restrict__ nk1,
    const float* __restrict__ hw1,
    float* __restrict__ ws_sc, float* __restrict__ ws_sv0, float* __restrict__ ws_sv1)
{
  const int i0 = blockIdx.x * kP;
  const int t  = threadIdx.x;
  __shared__ __align__(16) float f0s[kP][kD0];
  __shared__ __align__(16) float f1s[kP][kD1 * 3];
  __shared__ __align__(16) float q0s[kP][kHD];
  __shared__ __align__(16) float q1s[kP][kHD * 3];
  __shared__ float sk0L[kP][kHD];
  __shared__ float sk1L[kP][kHD * 3];
  __shared__ float w1s[kH];

  // ---- staging (all float4, coalesced) ----
  for (int u = t; u < kP * 32; u += 256) { int p = u >> 5, r = u & 31;
    ((float4*)f0s[p])[r] = ((const float4*)(feats0 + (size_t)(i0 + p) * kD0))[r]; }
  for (int u = t; u < kP * 48; u += 256) { int p = u / 48, r = u % 48;
    ((float4*)f1s[p])[r] = ((const float4*)(feats1 + (size_t)(i0 + p) * kD1 * 3))[r]; }
  for (int u = t; u < kP * 32; u += 256) { int p = u >> 5, r = u & 31;
    ((float4*)q0s[p])[r] = ((const float4*)(q0 + (size_t)(i0 + p) * kHD))[r]; }
  for (int u = t; u < kP * 96; u += 256) { int p = u / 96, r = u % 96;
    ((float4*)q1s[p])[r] = ((const float4*)(q1 + (size_t)(i0 + p) * kHD * 3))[r]; }
  if (t < kH) w1s[t] = log1pf(expf(hw1[t]));
  __syncthreads();

  // ---- W GEMV: row t, P positions in registers ----
  float acc0[kP] = {};
  {
    const float4* wr = (const float4*)(Wskv0 + t * kD0);
    #pragma unroll
    for (int g = 0; g < 32; ++g) {
      float4 w = wr[g]; int c = g * 4;
      #pragma unroll
      for (int p = 0; p < kP; ++p)
        acc0[p] += w.x * f0s[p][c] + w.y * f0s[p][c + 1]
                 + w.z * f0s[p][c + 2] + w.w * f0s[p][c + 3];
    }
  }
  float acc1[kP][3] = {};
  {
    const float4* wr = (const float4*)(Wskv1 + t * kD1);
    #pragma unroll
    for (int g = 0; g < 16; ++g) {
      float4 w = wr[g]; int c = g * 4;
      float wv[4] = {w.x, w.y, w.z, w.w};
      #pragma unroll
      for (int q = 0; q < 4; ++q) {
        #pragma unroll
        for (int p = 0; p < kP; ++p) {
          const float* fp = &f1s[p][(c + q) * 3];
          acc1[p][0] += wv[q] * fp[0];
          acc1[p][1] += wv[q] * fp[1];
          acc1[p][2] += wv[q] * fp[2];
        }
      }
    }
  }
  if (t < kHD) {
    #pragma unroll
    for (int p = 0; p < kP; ++p) {
      sk0L[p][t] = acc0[p];
      sk1L[p][t * 3 + 0] = acc1[p][0];
      sk1L[p][t * 3 + 1] = acc1[p][1];
      sk1L[p][t * 3 + 2] = acc1[p][2];
    }
  } else {
    const int o = t - kHD;
    #pragma unroll
    for (int p = 0; p < kP; ++p) {
      ws_sv0[(size_t)(i0 + p) * kHD + o] = acc0[p];
      float* sp = ws_sv1 + (size_t)(i0 + p) * kHD * 3 + o * 3;
      sp[0] = acc1[p][0]; sp[1] = acc1[p][1]; sp[2] = acc1[p][2];
    }
  }
  __syncthreads();

  // ---- null/self score slots ----
  if (t < kP * 16) {
    const int p = t >> 4, idx = t & 15;
    const int h = idx & 7;
    const bool is_self = idx >= 8;
    float s0 = 0.f, s1 = 0.f, bias;
    if (is_self) {
      #pragma unroll
      for (int d = 0; d < kD; ++d) s0 += q0s[p][h * kD + d] * sk0L[p][h * kD + d];
      #pragma unroll
      for (int x = 0; x < 48; ++x) s1 += q1s[p][h * 48 + x] * sk1L[p][h * 48 + x];
      bias = self_bias[h];
    } else {
      #pragma unroll
      for (int d = 0; d < kD; ++d) s0 += q0s[p][h * kD + d] * nk0[h * kD + d];
      #pragma unroll
      for (int x = 0; x < 48; ++x) s1 += q1s[p][h * 48 + x] * nk1[h * 48 + x];
      bias = null_bias[h];
    }
    float total = (s0 * SCALE0 + bias + s1 * SCALE1 * w1s[h]) * SHARED_S;
    ws_sc[(size_t)(i0 + p) * 272 + h * 34 + (is_self ? 1 : 0)] = total;
  }
}

// ---------------------------------------------------------------------------
// K2: neighbor similarities + fused softmax. P positions/block.
// ---------------------------------------------------------------------------
__global__ __launch_bounds__(256) void k2_sims(
    const float* __restrict__ q0, const float* __restrict__ q1,
    const float* __restrict__ k0, const float* __restrict__ k1,
    const float* __restrict__ edges, const float* __restrict__ Wbias,
    const float* __restrict__ hw1, const int* __restrict__ nmask,
    float* __restrict__ ws_sc)
{
  const int i0 = blockIdx.x * kP;
  const int t  = threadIdx.x;
  __shared__ float q0s[kP][kH * 17];     // [h*17+d] padded
  __shared__ float q1s[kP][kH * 49];     // [h*49+x] padded
  __shared__ float edg[kP][kN * 33];     // [j*33+e] padded
  __shared__ float wbT[kE * kH];         // [e*8+h]
  __shared__ float w1s[kH];
  __shared__ __align__(16) float scL[kP][272];

  // ---- staging ----
  for (int u = t; u < kP * 32; u += 256) { int p = u >> 5, r = u & 31;
    float4 v = ((const float4*)(q0 + (size_t)(i0 + p) * kHD))[r];
    int c = r * 4, h = c >> 4, d = c & 15;
    float* dst = &q0s[p][h * 17 + d];
    dst[0] = v.x; dst[1] = v.y; dst[2] = v.z; dst[3] = v.w; }
  for (int u = t; u < kP * 96; u += 256) { int p = u / 96, r = u % 96;
    float4 v = ((const float4*)(q1 + (size_t)(i0 + p) * kHD * 3))[r];
    int c = r * 4, h = c / 48, x = c % 48;
    float* dst = &q1s[p][h * 49 + x];
    dst[0] = v.x; dst[1] = v.y; dst[2] = v.z; dst[3] = v.w; }
  for (int u = t; u < kP * 256; u += 256) { int p = u >> 8, r = u & 255;
    float4 v = ((const float4*)(edges + (size_t)(i0 + p) * kN * kE))[r];
    int j = r >> 3, e4 = (r & 7) * 4;
    float* dst = &edg[p][j * 33 + e4];
    dst[0] = v.x; dst[1] = v.y; dst[2] = v.z; dst[3] = v.w; }
  if (t < kH * kE) { int h = t >> 5, e = t & 31; wbT[e * 8 + h] = Wbias[t]; }
  if (t < kH) w1s[t] = log1pf(expf(hw1[t]));
  if (t < kP * 16) { int p = t >> 4, idx = t & 15, h = idx & 7, slot = idx >> 3;
    scL[p][h * 34 + slot] = ws_sc[(size_t)(i0 + p) * 272 + h * 34 + slot]; }
  __syncthreads();

  // ---- neighbor sims: thread (j,h), loop P positions ----
  {
    const int j = t >> 3, h = t & 7;
    #pragma unroll
    for (int p = 0; p < kP; ++p) {
      const int i = i0 + p;
      float bias = 0.f;
      #pragma unroll
      for (int e = 0; e < kE; ++e) bias += edg[p][j * 33 + e] * wbT[e * 8 + h];
      float s0 = 0.f;
      const float4* kr0 = (const float4*)(k0 + (size_t)(i * kN + j) * kHD + h * kD);
      #pragma unroll
      for (int g = 0; g < 4; ++g) {
        float4 w = kr0[g]; int x = h * 17 + g * 4;
        s0 += w.x * q0s[p][x] + w.y * q0s[p][x + 1]
            + w.z * q0s[p][x + 2] + w.w * q0s[p][x + 3];
      }
      float s1 = 0.f;
      const float4* kr1 = (const float4*)(k1 + (size_t)(i * kN + j) * kHD * 3 + h * 48);
      #pragma unroll
      for (int g = 0; g < 12; ++g) {
        float4 w = kr1[g]; int x = h * 49 + g * 4;
        s1 += w.x * q1s[p][x] + w.y * q1s[p][x + 1]
            + w.z * q1s[p][x + 2] + w.w * q1s[p][x + 3];
      }
      float total = (s0 * SCALE0 + bias + s1 * SCALE1 * w1s[h]) * SHARED_S;
      bool valid = nmask[(size_t)i * kN + j] != 0;
      scL[p][h * 34 + 2 + j] = valid ? total : NEGV;
    }
  }
  __syncthreads();

  // ---- softmax per (p,h) ----
  if (t < kP * kH) {
    const int p = t >> 3, h = t & 7;
    float* row = &scL[p][h * 34];
    float mx = -1e30f;
    #pragma unroll
    for (int u = 0; u < 34; ++u) mx = fmaxf(mx, row[u]);
    float sum = 0.f;
    #pragma unroll
    for (int u = 0; u < 34; ++u) sum += __expf(row[u] - mx);
    float inv = 1.f / sum;
    #pragma unroll
    for (int u = 0; u < 34; ++u) row[u] = __expf(row[u] - mx) * inv;
  }
  __syncthreads();

  // ---- coalesced float4 writeback of attn rows ----
  for (int u = t; u < kP * 68; u += 256) {
    int p = u / 68, r = u % 68;
    ((float4*)(ws_sc + (size_t)(i0 + p) * 272))[r] = ((float4*)scL[p])[r];
  }
}

// ---------------------------------------------------------------------------
// K3: attn-weighted V accumulation + output projections. P positions/block.
// Pure float4 v-stream; attn staged in LDS; W rows reused across P positions.
// ---------------------------------------------------------------------------
__global__ __launch_bounds__(256) void k3_out(
    const float* __restrict__ v0, const float* __restrict__ v1,
    const float* __restrict__ nv0, const float* __restrict__ nv1,
    const float* __restrict__ ws_sc,
    const float* __restrict__ ws_sv0, const float* __restrict__ ws_sv1,
    const float* __restrict__ Wout0, const float* __restrict__ Wout1,
    float* __restrict__ out, int n_total)
{
  const int i0 = blockIdx.x * kP;
  const int t  = threadIdx.x;
  __shared__ __align__(16) float attnL[kP][272];
  __shared__ __align__(16) float o0L[kP][kHD];
  __shared__ __align__(16) float o1L[kP][kHD * 3];

  for (int u = t; u < kP * 68; u += 256) {
    int p = u / 68, r = u % 68;
    ((float4*)attnL[p])[r] = ((const float4*)(ws_sc + (size_t)(i0 + p) * 272))[r];
  }
  __syncthreads();

  // thread -> (half, slot): slot<32 deg0 float4-chunk, else deg1 chunk.
  // Each thread handles positions {half, half+2} serially.
  const int half = t >> 7, slot = t & 127;
  if (slot < 32) {
    const int s = slot, h = s >> 2;
    float4 nv = ((const float4*)nv0)[s];
    #pragma unroll
    for (int pi = 0; pi < 2; ++pi) {
      const int p = half + pi * 2, i = i0 + p;
      const float* at = attnL[p] + h * 34;
      float4 sv = ((const float4*)(ws_sv0 + (size_t)i * kHD))[s];
      float4 acc;
      acc.x = at[0] * nv.x + at[1] * sv.x;
      acc.y = at[0] * nv.y + at[1] * sv.y;
      acc.z = at[0] * nv.z + at[1] * sv.z;
      acc.w = at[0] * nv.w + at[1] * sv.w;
      const float4* vp = (const float4*)(v0 + (size_t)i * kN * kHD) + s;
      #pragma unroll
      for (int j = 0; j < kN; ++j) {
        float4 v = vp[j * 32];
        float a = at[2 + j];
        acc.x += a * v.x; acc.y += a * v.y; acc.z += a * v.z; acc.w += a * v.w;
      }
      ((float4*)o0L[p])[s] = acc;
    }
  } else {
    const int s = slot - 32;          // 0..95, never straddles a head (48%4==0)
    const int h = s / 12;
    float4 nv = ((const float4*)nv1)[s];
    #pragma unroll
    for (int pi = 0; pi < 2; ++pi) {
      const int p = half + pi * 2, i = i0 + p;
      const float* at = attnL[p] + h * 34;
      float4 sv = ((const float4*)(ws_sv1 + (size_t)i * kHD * 3))[s];
      float4 acc;
      acc.x = at[0] * nv.x + at[1] * sv.x;
      acc.y = at[0] * nv.y + at[1] * sv.y;
      acc.z = at[0] * nv.z + at[1] * sv.z;
      acc.w = at[0] * nv.w + at[1] * sv.w;
      const float4* vp = (const float4*)(v1 + (size_t)i * kN * kHD * 3) + s;
      #pragma unroll
      for (int j = 0; j < kN; ++j) {
        float4 v = vp[j * 96];
        float a = at[2 + j];
        acc.x += a * v.x; acc.y += a * v.y; acc.z += a * v.z; acc.w += a * v.w;
      }
      ((float4*)o1L[p])[s] = acc;
    }
  }
  __syncthreads();

  // ---- projections: thread owns output element, loops P positions (W reuse) --
  for (int u = t; u < 320; u += 256) {
    if (u < 128) {
      float acc[kP] = {};
      const float4* wr = (const float4*)(Wout0 + u * kHD);
      #pragma unroll
      for (int g = 0; g < 32; ++g) {
        float4 w = wr[g]; int c = g * 4;
        #pragma unroll
        for (int p = 0; p < kP; ++p)
          acc[p] += w.x * o0L[p][c] + w.y * o0L[p][c + 1]
                  + w.z * o0L[p][c + 2] + w.w * o0L[p][c + 3];
      }
      #pragma unroll
      for (int p = 0; p < kP; ++p) out[(size_t)(i0 + p) * kHD + u] = acc[p];
    } else {
      const int v2 = u - 128, o = v2 / 3, m = v2 - o * 3;
      float acc[kP] = {};
      const float4* wr = (const float4*)(Wout1 + o * kHD);
      #pragma unroll
      for (int g = 0; g < 32; ++g) {
        float4 w = wr[g]; int c = g * 4;
        #pragma unroll
        for (int p = 0; p < kP; ++p)
          acc[p] += w.x * o1L[p][(c + 0) * 3 + m] + w.y * o1L[p][(c + 1) * 3 + m]
                  + w.z * o1L[p][(c + 2) * 3 + m] + w.w * o1L[p][(c + 3) * 3 + m];
      }
      #pragma unroll
      for (int p = 0; p < kP; ++p)
        out[(size_t)n_total * kHD + (size_t)(i0 + p) * 192 + v2] = acc[p];
    }
  }
}

extern "C" void kernel_launch(void* const* d_in, const int* in_sizes, int n_in,
                              void* d_out, int out_size, void* d_ws, size_t ws_size,
                              hipStream_t stream) {
  const int n = in_sizes[0] / kHD;  // 2048
  const int nb = n / kP;            // 512 blocks
  const float* q0     = (const float*)d_in[0];
  const float* k0     = (const float*)d_in[1];
  const float* v0     = (const float*)d_in[2];
  const float* q1     = (const float*)d_in[3];
  const float* k1     = (const float*)d_in[4];
  const float* v1     = (const float*)d_in[5];
  const float* feats0 = (const float*)d_in[6];
  const float* feats1 = (const float*)d_in[7];
  const float* edges  = (const float*)d_in[8];
  const float* Wskv0  = (const float*)d_in[9];
  const float* Wskv1  = (const float*)d_in[10];
  const float* Wbias  = (const float*)d_in[11];
  const float* sbias  = (const float*)d_in[12];
  const float* nbias  = (const float*)d_in[13];
  const float* nk0    = (const float*)d_in[14];
  const float* nv0    = (const float*)d_in[15];
  const float* nk1    = (const float*)d_in[16];
  const float* nv1    = (const float*)d_in[17];
  const float* hw1    = (const float*)d_in[18];
  const float* Wout0  = (const float*)d_in[19];
  const float* Wout1  = (const float*)d_in[20];
  const int*   nmask  = (const int*)d_in[21];

  float* ws     = (float*)d_ws;
  float* ws_sc  = ws;                                      // n*272
  float* ws_sv0 = ws + (size_t)n * 272;                    // n*128
  float* ws_sv1 = ws + (size_t)n * 272 + (size_t)n * 128;  // n*384

  k1_selfkv<<<nb, 256, 0, stream>>>(q0, q1, feats0, feats1, Wskv0, Wskv1,
                                    sbias, nbias, nk0, nk1, hw1,
                                    ws_sc, ws_sv0, ws_sv1);
  k2_sims<<<nb, 256, 0, stream>>>(q0, q1, k0, k1, edges, Wbias, hw1, nmask, ws_sc);
  k3_out<<<nb, 256, 0, stream>>>(v0, v1, nv0, nv1, ws_sc, ws_sv0, ws_sv1,
                                 Wout0, Wout1, (float*)d_out, n);
}

// Round 5
// 368.613 us; speedup vs baseline: 1.0568x; 1.0363x over previous
//
#include <hip/hip_runtime.h>

// Problem constants
constexpr int kH  = 8;     // heads
constexpr int kD  = 16;    // dim per head
constexpr int kHD = 128;   // H*D
constexpr int kN  = 32;    // neighbors
constexpr int kE  = 32;    // edge feature dim
constexpr int kD0 = 128;   // feats0 channels
constexpr int kD1 = 64;    // feats1 channels
constexpr int kP  = 4;     // positions per block (k1,k2)
constexpr int kP3 = 2;     // positions per block (k3)

constexpr float SCALE0   = 0.25f;                 // 1/sqrt(16)
constexpr float SCALE1   = 0.14433756729740643f;  // 1/sqrt(48)
constexpr float SHARED_S = 0.70710678118654752f;  // sqrt(0.5)
constexpr float NEGV     = -1e9f;

// ws layout (floats): sc[n][272] | sv0[n][128] | sv1[n][384]

// ---------------------------------------------------------------------------
// K1: self key/value rows + null/self similarity score slots. P positions/block.
// ---------------------------------------------------------------------------
__global__ __launch_bounds__(256) void k1_selfkv(
    const float* __restrict__ q0, const float* __restrict__ q1,
    const float* __restrict__ feats0, const float* __restrict__ feats1,
    const float* __restrict__ Wskv0, const float* __restrict__ Wskv1,
    const float* __restrict__ self_bias, const float* __restrict__ null_bias,
    const float* __restrict__ nk0, const float* __restrict__ nk1,
    const float* __restrict__ hw1,
    float* __restrict__ ws_sc, float* __restrict__ ws_sv0, float* __restrict__ ws_sv1)
{
  const int i0 = blockIdx.x * kP;
  const int t  = threadIdx.x;
  __shared__ __align__(16) float f0s[kP][kD0];
  __shared__ __align__(16) float f1s[kP][kD1 * 3];
  __shared__ __align__(16) float q0s[kP][kHD];
  __shared__ __align__(16) float q1s[kP][kHD * 3];
  __shared__ float sk0L[kP][kHD];
  __shared__ float sk1L[kP][kHD * 3];
  __shared__ float w1s[kH];

  for (int u = t; u < kP * 32; u += 256) { int p = u >> 5, r = u & 31;
    ((float4*)f0s[p])[r] = ((const float4*)(feats0 + (size_t)(i0 + p) * kD0))[r]; }
  for (int u = t; u < kP * 48; u += 256) { int p = u / 48, r = u % 48;
    ((float4*)f1s[p])[r] = ((const float4*)(feats1 + (size_t)(i0 + p) * kD1 * 3))[r]; }
  for (int u = t; u < kP * 32; u += 256) { int p = u >> 5, r = u & 31;
    ((float4*)q0s[p])[r] = ((const float4*)(q0 + (size_t)(i0 + p) * kHD))[r]; }
  for (int u = t; u < kP * 96; u += 256) { int p = u / 96, r = u % 96;
    ((float4*)q1s[p])[r] = ((const float4*)(q1 + (size_t)(i0 + p) * kHD * 3))[r]; }
  if (t < kH) w1s[t] = log1pf(expf(hw1[t]));
  __syncthreads();

  float acc0[kP] = {};
  {
    const float4* wr = (const float4*)(Wskv0 + t * kD0);
    #pragma unroll
    for (int g = 0; g < 32; ++g) {
      float4 w = wr[g]; int c = g * 4;
      #pragma unroll
      for (int p = 0; p < kP; ++p)
        acc0[p] += w.x * f0s[p][c] + w.y * f0s[p][c + 1]
                 + w.z * f0s[p][c + 2] + w.w * f0s[p][c + 3];
    }
  }
  float acc1[kP][3] = {};
  {
    const float4* wr = (const float4*)(Wskv1 + t * kD1);
    #pragma unroll
    for (int g = 0; g < 16; ++g) {
      float4 w = wr[g]; int c = g * 4;
      float wv[4] = {w.x, w.y, w.z, w.w};
      #pragma unroll
      for (int q = 0; q < 4; ++q) {
        #pragma unroll
        for (int p = 0; p < kP; ++p) {
          const float* fp = &f1s[p][(c + q) * 3];
          acc1[p][0] += wv[q] * fp[0];
          acc1[p][1] += wv[q] * fp[1];
          acc1[p][2] += wv[q] * fp[2];
        }
      }
    }
  }
  if (t < kHD) {
    #pragma unroll
    for (int p = 0; p < kP; ++p) {
      sk0L[p][t] = acc0[p];
      sk1L[p][t * 3 + 0] = acc1[p][0];
      sk1L[p][t * 3 + 1] = acc1[p][1];
      sk1L[p][t * 3 + 2] = acc1[p][2];
    }
  } else {
    const int o = t - kHD;
    #pragma unroll
    for (int p = 0; p < kP; ++p) {
      ws_sv0[(size_t)(i0 + p) * kHD + o] = acc0[p];
      float* sp = ws_sv1 + (size_t)(i0 + p) * kHD * 3 + o * 3;
      sp[0] = acc1[p][0]; sp[1] = acc1[p][1]; sp[2] = acc1[p][2];
    }
  }
  __syncthreads();

  if (t < kP * 16) {
    const int p = t >> 4, idx = t & 15;
    const int h = idx & 7;
    const bool is_self = idx >= 8;
    float s0 = 0.f, s1 = 0.f, bias;
    if (is_self) {
      #pragma unroll
      for (int d = 0; d < kD; ++d) s0 += q0s[p][h * kD + d] * sk0L[p][h * kD + d];
      #pragma unroll
      for (int x = 0; x < 48; ++x) s1 += q1s[p][h * 48 + x] * sk1L[p][h * 48 + x];
      bias = self_bias[h];
    } else {
      #pragma unroll
      for (int d = 0; d < kD; ++d) s0 += q0s[p][h * kD + d] * nk0[h * kD + d];
      #pragma unroll
      for (int x = 0; x < 48; ++x) s1 += q1s[p][h * 48 + x] * nk1[h * 48 + x];
      bias = null_bias[h];
    }
    float total = (s0 * SCALE0 + bias + s1 * SCALE1 * w1s[h]) * SHARED_S;
    ws_sc[(size_t)(i0 + p) * 272 + h * 34 + (is_self ? 1 : 0)] = total;
  }
}

// ---------------------------------------------------------------------------
// K2: neighbor similarities + fused softmax. P positions/block.
// ---------------------------------------------------------------------------
__global__ __launch_bounds__(256) void k2_sims(
    const float* __restrict__ q0, const float* __restrict__ q1,
    const float* __restrict__ k0, const float* __restrict__ k1,
    const float* __restrict__ edges, const float* __restrict__ Wbias,
    const float* __restrict__ hw1, const int* __restrict__ nmask,
    float* __restrict__ ws_sc)
{
  const int i0 = blockIdx.x * kP;
  const int t  = threadIdx.x;
  __shared__ float q0s[kP][kH * 17];
  __shared__ float q1s[kP][kH * 49];
  __shared__ float edg[kP][kN * 33];
  __shared__ float wbT[kE * kH];
  __shared__ float w1s[kH];
  __shared__ __align__(16) float scL[kP][272];

  for (int u = t; u < kP * 32; u += 256) { int p = u >> 5, r = u & 31;
    float4 v = ((const float4*)(q0 + (size_t)(i0 + p) * kHD))[r];
    int c = r * 4, h = c >> 4, d = c & 15;
    float* dst = &q0s[p][h * 17 + d];
    dst[0] = v.x; dst[1] = v.y; dst[2] = v.z; dst[3] = v.w; }
  for (int u = t; u < kP * 96; u += 256) { int p = u / 96, r = u % 96;
    float4 v = ((const float4*)(q1 + (size_t)(i0 + p) * kHD * 3))[r];
    int c = r * 4, h = c / 48, x = c % 48;
    float* dst = &q1s[p][h * 49 + x];
    dst[0] = v.x; dst[1] = v.y; dst[2] = v.z; dst[3] = v.w; }
  for (int u = t; u < kP * 256; u += 256) { int p = u >> 8, r = u & 255;
    float4 v = ((const float4*)(edges + (size_t)(i0 + p) * kN * kE))[r];
    int j = r >> 3, e4 = (r & 7) * 4;
    float* dst = &edg[p][j * 33 + e4];
    dst[0] = v.x; dst[1] = v.y; dst[2] = v.z; dst[3] = v.w; }
  if (t < kH * kE) { int h = t >> 5, e = t & 31; wbT[e * 8 + h] = Wbias[t]; }
  if (t < kH) w1s[t] = log1pf(expf(hw1[t]));
  if (t < kP * 16) { int p = t >> 4, idx = t & 15, h = idx & 7, slot = idx >> 3;
    scL[p][h * 34 + slot] = ws_sc[(size_t)(i0 + p) * 272 + h * 34 + slot]; }
  __syncthreads();

  {
    const int j = t >> 3, h = t & 7;
    #pragma unroll
    for (int p = 0; p < kP; ++p) {
      const int i = i0 + p;
      float bias = 0.f;
      #pragma unroll
      for (int e = 0; e < kE; ++e) bias += edg[p][j * 33 + e] * wbT[e * 8 + h];
      float s0 = 0.f;
      const float4* kr0 = (const float4*)(k0 + (size_t)(i * kN + j) * kHD + h * kD);
      #pragma unroll
      for (int g = 0; g < 4; ++g) {
        float4 w = kr0[g]; int x = h * 17 + g * 4;
        s0 += w.x * q0s[p][x] + w.y * q0s[p][x + 1]
            + w.z * q0s[p][x + 2] + w.w * q0s[p][x + 3];
      }
      float s1 = 0.f;
      const float4* kr1 = (const float4*)(k1 + (size_t)(i * kN + j) * kHD * 3 + h * 48);
      #pragma unroll
      for (int g = 0; g < 12; ++g) {
        float4 w = kr1[g]; int x = h * 49 + g * 4;
        s1 += w.x * q1s[p][x] + w.y * q1s[p][x + 1]
            + w.z * q1s[p][x + 2] + w.w * q1s[p][x + 3];
      }
      float total = (s0 * SCALE0 + bias + s1 * SCALE1 * w1s[h]) * SHARED_S;
      bool valid = nmask[(size_t)i * kN + j] != 0;
      scL[p][h * 34 + 2 + j] = valid ? total : NEGV;
    }
  }
  __syncthreads();

  if (t < kP * kH) {
    const int p = t >> 3, h = t & 7;
    float* row = &scL[p][h * 34];
    float mx = -1e30f;
    #pragma unroll
    for (int u = 0; u < 34; ++u) mx = fmaxf(mx, row[u]);
    float sum = 0.f;
    #pragma unroll
    for (int u = 0; u < 34; ++u) sum += __expf(row[u] - mx);
    float inv = 1.f / sum;
    #pragma unroll
    for (int u = 0; u < 34; ++u) row[u] = __expf(row[u] - mx) * inv;
  }
  __syncthreads();

  for (int u = t; u < kP * 68; u += 256) {
    int p = u / 68, r = u % 68;
    ((float4*)(ws_sc + (size_t)(i0 + p) * 272))[r] = ((float4*)scL[p])[r];
  }
}

// ---------------------------------------------------------------------------
// K3: attn-weighted V accumulation + output projections. kP3=2 positions/block.
// One (position, float4-chunk) per thread; batched loads (8 in flight).
// ---------------------------------------------------------------------------
__global__ __launch_bounds__(256) void k3_out(
    const float* __restrict__ v0, const float* __restrict__ v1,
    const float* __restrict__ nv0, const float* __restrict__ nv1,
    const float* __restrict__ ws_sc,
    const float* __restrict__ ws_sv0, const float* __restrict__ ws_sv1,
    const float* __restrict__ Wout0, const float* __restrict__ Wout1,
    float* __restrict__ out, int n_total)
{
  const int i0 = blockIdx.x * kP3;
  const int t  = threadIdx.x;
  __shared__ __align__(16) float attnL[kP3][272];
  __shared__ __align__(16) float o0L[kP3][kHD];
  __shared__ __align__(16) float o1L[kP3][kHD * 3];

  if (t < kP3 * 68) {
    int p = t / 68, r = t % 68;
    ((float4*)attnL[p])[r] = ((const float4*)(ws_sc + (size_t)(i0 + p) * 272))[r];
  }
  __syncthreads();

  // thread -> (p, s): p = t>>7, s = t&127. s<32: deg0 chunk s; else deg1 chunk s-32.
  {
    const int p = t >> 7, i = i0 + p;
    const int s = t & 127;
    float4 acc;
    if (s < 32) {
      const int h = s >> 2;
      const float* at = attnL[p] + h * 34;
      float4 nv = ((const float4*)nv0)[s];
      float4 sv = ((const float4*)(ws_sv0 + (size_t)i * kHD))[s];
      acc.x = at[0] * nv.x + at[1] * sv.x;
      acc.y = at[0] * nv.y + at[1] * sv.y;
      acc.z = at[0] * nv.z + at[1] * sv.z;
      acc.w = at[0] * nv.w + at[1] * sv.w;
      const float4* vp = (const float4*)(v0 + (size_t)i * kN * kHD) + s;
      float4 vbuf[8];
      #pragma unroll
      for (int g = 0; g < 4; ++g) {
        #pragma unroll
        for (int r = 0; r < 8; ++r) vbuf[r] = vp[(g * 8 + r) * 32];
        #pragma unroll
        for (int r = 0; r < 8; ++r) {
          float a = at[2 + g * 8 + r];
          acc.x += a * vbuf[r].x; acc.y += a * vbuf[r].y;
          acc.z += a * vbuf[r].z; acc.w += a * vbuf[r].w;
        }
      }
      ((float4*)o0L[p])[s] = acc;
    } else {
      const int s1 = s - 32;            // 0..95, never straddles a head (48%4==0)
      const int h = s1 / 12;
      const float* at = attnL[p] + h * 34;
      float4 nv = ((const float4*)nv1)[s1];
      float4 sv = ((const float4*)(ws_sv1 + (size_t)i * kHD * 3))[s1];
      acc.x = at[0] * nv.x + at[1] * sv.x;
      acc.y = at[0] * nv.y + at[1] * sv.y;
      acc.z = at[0] * nv.z + at[1] * sv.z;
      acc.w = at[0] * nv.w + at[1] * sv.w;
      const float4* vp = (const float4*)(v1 + (size_t)i * kN * kHD * 3) + s1;
      float4 vbuf[8];
      #pragma unroll
      for (int g = 0; g < 4; ++g) {
        #pragma unroll
        for (int r = 0; r < 8; ++r) vbuf[r] = vp[(g * 8 + r) * 96];
        #pragma unroll
        for (int r = 0; r < 8; ++r) {
          float a = at[2 + g * 8 + r];
          acc.x += a * vbuf[r].x; acc.y += a * vbuf[r].y;
          acc.z += a * vbuf[r].z; acc.w += a * vbuf[r].w;
        }
      }
      ((float4*)o1L[p])[s1] = acc;
    }
  }
  __syncthreads();

  // projections: thread owns output element, loops kP3 positions (W reuse)
  for (int u = t; u < 320; u += 256) {
    if (u < 128) {
      float acc[kP3] = {};
      const float4* wr = (const float4*)(Wout0 + u * kHD);
      #pragma unroll
      for (int g = 0; g < 32; ++g) {
        float4 w = wr[g]; int c = g * 4;
        #pragma unroll
        for (int p = 0; p < kP3; ++p)
          acc[p] += w.x * o0L[p][c] + w.y * o0L[p][c + 1]
                  + w.z * o0L[p][c + 2] + w.w * o0L[p][c + 3];
      }
      #pragma unroll
      for (int p = 0; p < kP3; ++p) out[(size_t)(i0 + p) * kHD + u] = acc[p];
    } else {
      const int v2 = u - 128, o = v2 / 3, m = v2 - o * 3;
      float acc[kP3] = {};
      const float4* wr = (const float4*)(Wout1 + o * kHD);
      #pragma unroll
      for (int g = 0; g < 32; ++g) {
        float4 w = wr[g]; int c = g * 4;
        #pragma unroll
        for (int p = 0; p < kP3; ++p)
          acc[p] += w.x * o1L[p][(c + 0) * 3 + m] + w.y * o1L[p][(c + 1) * 3 + m]
                  + w.z * o1L[p][(c + 2) * 3 + m] + w.w * o1L[p][(c + 3) * 3 + m];
      }
      #pragma unroll
      for (int p = 0; p < kP3; ++p)
        out[(size_t)n_total * kHD + (size_t)(i0 + p) * 192 + v2] = acc[p];
    }
  }
}

extern "C" void kernel_launch(void* const* d_in, const int* in_sizes, int n_in,
                              void* d_out, int out_size, void* d_ws, size_t ws_size,
                              hipStream_t stream) {
  const int n = in_sizes[0] / kHD;  // 2048
  const float* q0     = (const float*)d_in[0];
  const float* k0     = (const float*)d_in[1];
  const float* v0     = (const float*)d_in[2];
  const float* q1     = (const float*)d_in[3];
  const float* k1     = (const float*)d_in[4];
  const float* v1     = (const float*)d_in[5];
  const float* feats0 = (const float*)d_in[6];
  const float* feats1 = (const float*)d_in[7];
  const float* edges  = (const float*)d_in[8];
  const float* Wskv0  = (const float*)d_in[9];
  const float* Wskv1  = (const float*)d_in[10];
  const float* Wbias  = (const float*)d_in[11];
  const float* sbias  = (const float*)d_in[12];
  const float* nbias  = (const float*)d_in[13];
  const float* nk0    = (const float*)d_in[14];
  const float* nv0    = (const float*)d_in[15];
  const float* nk1    = (const float*)d_in[16];
  const float* nv1    = (const float*)d_in[17];
  const float* hw1    = (const float*)d_in[18];
  const float* Wout0  = (const float*)d_in[19];
  const float* Wout1  = (const float*)d_in[20];
  const int*   nmask  = (const int*)d_in[21];

  float* ws     = (float*)d_ws;
  float* ws_sc  = ws;                                      // n*272
  float* ws_sv0 = ws + (size_t)n * 272;                    // n*128
  float* ws_sv1 = ws + (size_t)n * 272 + (size_t)n * 128;  // n*384

  k1_selfkv<<<n / kP, 256, 0, stream>>>(q0, q1, feats0, feats1, Wskv0, Wskv1,
                                        sbias, nbias, nk0, nk1, hw1,
                                        ws_sc, ws_sv0, ws_sv1);
  k2_sims<<<n / kP, 256, 0, stream>>>(q0, q1, k0, k1, edges, Wbias, hw1, nmask, ws_sc);
  k3_out<<<n / kP3, 256, 0, stream>>>(v0, v1, nv0, nv1, ws_sc, ws_sv0, ws_sv1,
                                      Wout0, Wout1, (float*)d_out, n);
}